// Round 10
// baseline (134.873 us; speedup 1.0000x reference)
//
#include <hip/hip_runtime.h>

#define NX 352
#define NY 256
#define NZ 64

__device__ __forceinline__ float rcpf(float x) { return __builtin_amdgcn_rcpf(x); }

__device__ __forceinline__ float limiter(float cr) {
    return fmaxf(0.f, fmaxf(fminf(1.f, 2.f * cr), fminf(2.f, cr)));
}

__device__ __forceinline__ float sbflux(float vm1, float v0, float vp1, float vp2,
                                        float mm1, float m0, float mp1,
                                        float vel, float velfac, float rinv_dx)
{
    float rjp = (vp2 - vp1) * mp1;
    float rj  = (vp1 - v0) * m0;
    float rjm = (v0 - vm1) * mm1;
    float fv = velfac * vel;
    float uCFL = fabsf(fv * rinv_dx);
    float rden = (fabsf(rj) < 1e-20f) ? 1e-20f : rj;
    float cr = limiter(((vel > 0.f) ? rjm : rjp) * rcpf(rden));
    return fv * (vp1 + v0) * 0.5f - fabsf(fv) * ((1.f - cr) + uCFL * cr) * rj * 0.5f;
}

__device__ __forceinline__ float zflux(float t, float mw, float wv, int lane, float inv_dzwk)
{
    float t_km1 = __shfl_up(t, 1),  t_kp1 = __shfl_down(t, 1),  t_kp2 = __shfl_down(t, 2);
    float m_km1 = __shfl_up(mw, 1), m_kp1 = __shfl_down(mw, 1), m_kp2 = __shfl_down(mw, 2);
    float mm1 = (lane >= 1) ? mw * m_km1 : 0.f;
    float m0  = m_kp1 * mw;
    float mp1 = (lane + 1 < NZ - 1) ? m_kp2 * m_kp1 : 0.f;
    return sbflux(t_km1, t, t_kp1, t_kp2, mm1, m0, mp1, wv, 1.f, inv_dzwk);
}

__device__ __forceinline__ float vertdiv(float ft, int lane, float inv_dzwk, float inv_dzw_last)
{
    float ftm1 = __shfl_up(ft, 1);
    if (lane == 0) return -ft * inv_dzwk;
    if (lane < NZ - 1) return -(ft - ftm1) * inv_dzwk;
    return ftm1 * inv_dzw_last;
}

__device__ __forceinline__ void tri_setup(float tk_tau, float kap, float mx, float fo,
                                          float fs, int ks, int lane,
                                          float inv_dzwk, float inv_dzw_last, float inv_dzt_p,
                                          float &A, float &C, float &D, bool &water)
{
    float kp = __shfl_down(kap, 1);
    float delta = (lane < NZ - 1) ? 0.5f * (kap + kp) * inv_dzt_p : 0.f;
    float dm = __shfl_up(delta, 1); if (lane == 0) dm = 0.f;
    float diss = 0.7f * sqrtf(fmaxf(0.f, tk_tau)) * rcpf(mx);
    float a, b;
    if (lane == 0)          { a = 0.f; b = 0.f; }
    else if (lane < NZ - 1) { a = -dm * inv_dzwk; b = 1.f + (delta + dm) * inv_dzwk + diss; }
    else                    { a = -dm * inv_dzw_last; b = 1.f + dm * inv_dzw_last + diss; }
    float bE = 1.f + delta * inv_dzwk + diss;
    float c  = (lane < NZ - 1) ? -delta * inv_dzwk : 0.f;
    float d  = tk_tau + fo;
    if (lane == NZ - 1) d += fs * inv_dzw_last;
    bool land = (ks >= 0);
    water = land && (lane >= ks);
    bool edge = land && (lane == ks);
    float At = (water && !edge) ? a : 0.f;
    float Bt = edge ? bE : (water ? b : 1.f);
    float Ct = water ? c : 0.f;
    float Dt = water ? d : 0.f;
    float r = rcpf(Bt);
    A = At * r; C = Ct * r; D = Dt * r;
}

__device__ __forceinline__ void pcr_step(float &A, float &C, float &D, int s, bool lo, bool hi)
{
    float am = __shfl_up(A, s),   cm = __shfl_up(C, s),   dm = __shfl_up(D, s);
    float ap = __shfl_down(A, s), cp = __shfl_down(C, s), dp = __shfl_down(D, s);
    if (lo) { am = 0.f; cm = 0.f; dm = 0.f; }
    if (hi) { ap = 0.f; cp = 0.f; dp = 0.f; }
    float r = rcpf(1.f - A * cm - C * ap);
    float nA = -A * am * r, nC = -C * cp * r;
    float nD = (D - A * dm - C * dp) * r;
    A = nA; C = nC; D = nD;
}

__global__ __launch_bounds__(256) void
tke_fused(const float* __restrict__ tke, const float* __restrict__ dtke,
          const float* __restrict__ u, const float* __restrict__ v,
          const float* __restrict__ w,
          const float* __restrict__ maskU, const float* __restrict__ maskV,
          const float* __restrict__ maskW,
          const float* __restrict__ kappaM, const float* __restrict__ mxl,
          const float* __restrict__ forc, const float* __restrict__ forc_surf,
          const int* __restrict__ kbot,
          const float* __restrict__ dxt, const float* __restrict__ dxu,
          const float* __restrict__ dyt, const float* __restrict__ dyu,
          const float* __restrict__ dzt, const float* __restrict__ dzw,
          const float* __restrict__ cost, const float* __restrict__ cosu,
          float* __restrict__ out_tke, float* __restrict__ out_dtke,
          float* __restrict__ out_corr)
{
    const int lane = threadIdx.x;                    // k, 0..63
    // XCD-aware swizzle: 11264 blocks = 8 * 1408 (bijective)
    int bid = blockIdx.x;
    bid = (bid & 7) * 1408 + (bid >> 3);
    // pair id is wave-uniform: force scalarization so all derived indexing is SALU/SGPR
    const int pr = __builtin_amdgcn_readfirstlane(bid * 4 + (int)threadIdx.y);
    const int ip = pr >> 8;                          // NY = 256
    const int j  = pr & 255;
    const int i0 = ip << 1;                          // even; pair (i0, i0+1)
    const bool interior = (i0 >= 2 && i0 < NX - 2 && j >= 2 && j < NY - 2); // wave-uniform

    const unsigned SX = (unsigned)NY * NZ;
    const unsigned colA = (unsigned)(i0 * NY + j);
    const unsigned colB = colA + NY;
    const unsigned cA = colA * NZ;                   // uniform column bases
    const unsigned cB = cA + SX;
    const unsigned l1 = (unsigned)lane;
    const unsigned l3 = 3u * l1;

    const float3 tkA = *reinterpret_cast<const float3*>(tke + 3u * cA + l3);
    const float3 tkB = *reinterpret_cast<const float3*>(tke + 3u * cB + l3);
    const float3 dtA = *reinterpret_cast<const float3*>(dtke + 3u * cA + l3);
    const float3 dtB = *reinterpret_cast<const float3*>(dtke + 3u * cB + l3);

    if (!interior) {
        // wave-uniform passthrough: AB update from unchanged dtke, copy the rest
        float3 ot, od;
        ot.x = tkA.x; ot.y = tkA.y + 1.6f * dtA.x - 0.6f * dtA.z; ot.z = tkA.z;
        *reinterpret_cast<float3*>(out_tke + 3u * cA + l3) = ot;
        ot.x = tkB.x; ot.y = tkB.y + 1.6f * dtB.x - 0.6f * dtB.z; ot.z = tkB.z;
        *reinterpret_cast<float3*>(out_tke + 3u * cB + l3) = ot;
        od.x = dtA.x; od.y = dtA.y; od.z = dtA.z;
        *reinterpret_cast<float3*>(out_dtke + 3u * cA + l3) = od;
        od.x = dtB.x; od.y = dtB.y; od.z = dtB.z;
        *reinterpret_cast<float3*>(out_dtke + 3u * cB + l3) = od;
        if (lane == NZ - 1) { out_corr[colA] = 0.f; out_corr[colB] = 0.f; }
        return;
    }

    // ---------- stencil loads (all bases uniform; offset = lane only) ----------
    const float t_m2 = tke[3u * (cA - 2u * SX) + l3], t_m1 = tke[3u * (cA - SX) + l3];
    const float t_p2 = tke[3u * (cB + SX) + l3],      t_p3 = tke[3u * (cB + 2u * SX) + l3];
    const float mw_m2 = maskW[cA - 2u * SX + l1], mw_m1 = maskW[cA - SX + l1];
    const float mwA = maskW[cA + l1], mwB = maskW[cB + l1];
    const float mw_p2 = maskW[cB + SX + l1], mw_p3 = maskW[cB + 2u * SX + l1];

    const float tA_ym2 = tke[3u * (cA - 2u * NZ) + l3], tA_ym1 = tke[3u * (cA - NZ) + l3];
    const float tA_yp1 = tke[3u * (cA + NZ) + l3],      tA_yp2 = tke[3u * (cA + 2u * NZ) + l3];
    const float tB_ym2 = tke[3u * (cB - 2u * NZ) + l3], tB_ym1 = tke[3u * (cB - NZ) + l3];
    const float tB_yp1 = tke[3u * (cB + NZ) + l3],      tB_yp2 = tke[3u * (cB + 2u * NZ) + l3];
    const float mwA_ym2 = maskW[cA - 2u * NZ + l1], mwA_ym1 = maskW[cA - NZ + l1];
    const float mwA_yp1 = maskW[cA + NZ + l1],      mwA_yp2 = maskW[cA + 2u * NZ + l1];
    const float mwB_ym2 = maskW[cB - 2u * NZ + l1], mwB_ym1 = maskW[cB - NZ + l1];
    const float mwB_yp1 = maskW[cB + NZ + l1],      mwB_yp2 = maskW[cB + 2u * NZ + l1];

    const float uA0 = u[3u * (cA - SX) + l3], uA1 = u[3u * cA + l3], uB1 = u[3u * cB + l3];
    const float vA0 = v[3u * (cA - NZ) + l3], vA1 = v[3u * cA + l3];
    const float vB0 = v[3u * (cB - NZ) + l3], vB1 = v[3u * cB + l3];
    const float wA = w[3u * cA + l3], wB = w[3u * cB + l3];
    const float mUA0 = maskU[cA - SX + l1], mUA1 = maskU[cA + l1], mUB1 = maskU[cB + l1];
    const float mVA0 = maskV[cA - NZ + l1], mVA1 = maskV[cA + l1];
    const float mVB0 = maskV[cB - NZ + l1], mVB1 = maskV[cB + l1];

    // tridiag inputs
    const float kapA = kappaM[cA + l1], kapB = kappaM[cB + l1];
    const float mxA = mxl[cA + l1], mxB = mxl[cB + l1];
    const float foA = forc[cA + l1], foB = forc[cB + l1];
    const int   ksA = kbot[colA] - 1, ksB = kbot[colB] - 1;
    const float fsA = forc_surf[colA], fsB = forc_surf[colB];

    // lane constants
    const float dzwk         = dzw[lane];
    const float inv_dzwk     = rcpf(dzwk);
    const float dzw_last     = 0.5f * dzw[NZ - 1];
    const float inv_dzw_last = rcpf(dzw_last);
    const float inv_dzt_p    = rcpf(dzt[(lane < NZ - 1) ? lane + 1 : NZ - 1]);

    // geometry (all scalar loads; uniform indices)
    const float cj = cost[j];
    const float rdx_m = rcpf(cj * dxt[i0 - 1]);
    const float rdx_0 = rcpf(cj * dxt[i0]);
    const float rdx_1 = rcpf(cj * dxt[i0 + 1]);
    const float rdy_j  = rcpf(cj * dyt[j]);
    const float rdy_jm = rcpf(cost[j - 1] * dyt[j - 1]);
    const float cu_j = cosu[j], cu_jm = cosu[j - 1];
    const float cud_j  = cu_j * rcpf(dyu[j]);
    const float cud_jm = cu_jm * rcpf(dyu[j - 1]);
    const float rdxu_m = rcpf(cj * dxu[i0 - 1]);
    const float rdxu_0 = rcpf(cj * dxu[i0]);
    const float rdxu_1 = rcpf(cj * dxu[i0 + 1]);

    // ---------- x advection: 3 interface fluxes (middle shared) ----------
    const float mxf_m1 = mwA * mw_m1;
    const float mxf_0  = mwB * mwA;
    const float mxf_p1 = mw_p2 * mwB;
    float feA0 = sbflux(t_m2, t_m1, tkA.x, tkB.x,
                        mw_m1 * mw_m2, mxf_m1, mxf_0, uA0, 1.f, rdx_m);
    float feI  = sbflux(t_m1, tkA.x, tkB.x, t_p2,
                        mxf_m1, mxf_0, mxf_p1, uA1, 1.f, rdx_0);
    float feB1 = sbflux(tkA.x, tkB.x, t_p2, t_p3,
                        mxf_0, mxf_p1, mw_p3 * mw_p2, uB1, 1.f, rdx_1);

    // ---------- y advection per column ----------
    float fnA0 = sbflux(tA_ym2, tA_ym1, tkA.x, tA_yp1,
                        mwA_ym1 * mwA_ym2, mwA * mwA_ym1, mwA_yp1 * mwA,
                        vA0, cu_jm, rdy_jm);
    float fnA1 = sbflux(tA_ym1, tkA.x, tA_yp1, tA_yp2,
                        mwA * mwA_ym1, mwA_yp1 * mwA, mwA_yp2 * mwA_yp1,
                        vA1, cu_j, rdy_j);
    float fnB0 = sbflux(tB_ym2, tB_ym1, tkB.x, tB_yp1,
                        mwB_ym1 * mwB_ym2, mwB * mwB_ym1, mwB_yp1 * mwB,
                        vB0, cu_jm, rdy_jm);
    float fnB1 = sbflux(tB_ym1, tkB.x, tB_yp1, tB_yp2,
                        mwB * mwB_ym1, mwB_yp1 * mwB, mwB_yp2 * mwB_yp1,
                        vB1, cu_j, rdy_j);

    // ---------- z advection per column ----------
    float vertA = vertdiv(zflux(tkA.x, mwA, wA, lane, inv_dzwk), lane, inv_dzwk, inv_dzw_last);
    float vertB = vertdiv(zflux(tkB.x, mwB, wB, lane, inv_dzwk), lane, inv_dzwk, inv_dzw_last);

    float horA = mwA * (-(feI - feA0) * rdx_0 - (fnA1 - fnA0) * rdy_j);
    float horB = mwB * (-(feB1 - feI) * rdx_1 - (fnB1 - fnB0) * rdy_j);

    // ---------- horizontal diffusion ----------
    float feDm = 2000.f * (tkA.x - t_m1)  * rdxu_m * mUA0;
    float feD0 = 2000.f * (tkB.x - tkA.x) * rdxu_0 * mUA1;
    float feDp = 2000.f * (t_p2 - tkB.x)  * rdxu_1 * mUB1;
    float fnD1A = 2000.f * (tA_yp1 - tkA.x) * cud_j  * mVA1;
    float fnD0A = 2000.f * (tkA.x - tA_ym1) * cud_jm * mVA0;
    float fnD1B = 2000.f * (tB_yp1 - tkB.x) * cud_j  * mVB1;
    float fnD0B = 2000.f * (tkB.x - tB_ym1) * cud_jm * mVB0;
    float diffA = mwA * ((feD0 - feDm) * rdx_0 + (fnD1A - fnD0A) * rdy_j);
    float diffB = mwB * ((feDp - feD0) * rdx_1 + (fnD1B - fnD0B) * rdy_j);

    const float dtkeA = horA + vertA;
    const float dtkeB = horB + vertB;

    // ---------- early dtke stores (shrink live set across PCR) ----------
    float3 od;
    od.x = dtkeA; od.y = dtA.y; od.z = dtA.z;
    *reinterpret_cast<float3*>(out_dtke + 3u * cA + l3) = od;
    od.x = dtkeB; od.y = dtB.y; od.z = dtB.z;
    *reinterpret_cast<float3*>(out_dtke + 3u * cB + l3) = od;

    const float restA = diffA + 1.6f * dtkeA - 0.6f * dtA.z;
    const float restB = diffB + 1.6f * dtkeB - 0.6f * dtB.z;

    // ---------- tridiag setup + 2-chain PCR ----------
    float A0, C0, D0, A1c, C1c, D1c;
    bool waterA, waterB;
    tri_setup(tkA.x, kapA, mxA, foA, fsA, ksA, lane,
              inv_dzwk, inv_dzw_last, inv_dzt_p, A0, C0, D0, waterA);
    tri_setup(tkB.x, kapB, mxB, foB, fsB, ksB, lane,
              inv_dzwk, inv_dzw_last, inv_dzt_p, A1c, C1c, D1c, waterB);

    #pragma unroll
    for (int s = 1; s < NZ; s <<= 1) {
        const bool lo = (lane < s);
        const bool hi = (lane + s >= NZ);
        pcr_step(A0, C0, D0, s, lo, hi);
        pcr_step(A1c, C1c, D1c, s, lo, hi);
    }

    float partialA = waterA ? D0 : tkA.y;
    float partialB = waterB ? D1c : tkB.y;
    if (lane == NZ - 1) {
        float corrA = 0.f, corrB = 0.f;
        if (partialA < 0.f) { corrA = -partialA * dzw_last; partialA = 0.f; }
        if (partialB < 0.f) { corrB = -partialB * dzw_last; partialB = 0.f; }
        out_corr[colA] = corrA;
        out_corr[colB] = corrB;
    }

    // ---------- dense final stores ----------
    float3 ot;
    ot.x = tkA.x; ot.y = partialA + restA; ot.z = tkA.z;
    *reinterpret_cast<float3*>(out_tke + 3u * cA + l3) = ot;
    ot.x = tkB.x; ot.y = partialB + restB; ot.z = tkB.z;
    *reinterpret_cast<float3*>(out_tke + 3u * cB + l3) = ot;
}

extern "C" void kernel_launch(void* const* d_in, const int* in_sizes, int n_in,
                              void* d_out, int out_size, void* d_ws, size_t ws_size,
                              hipStream_t stream)
{
    const float* u         = (const float*)d_in[0];
    const float* v         = (const float*)d_in[1];
    const float* w         = (const float*)d_in[2];
    const float* maskU     = (const float*)d_in[3];
    const float* maskV     = (const float*)d_in[4];
    const float* maskW     = (const float*)d_in[5];
    const float* dxt       = (const float*)d_in[6];
    const float* dxu       = (const float*)d_in[7];
    const float* dyt       = (const float*)d_in[8];
    const float* dyu       = (const float*)d_in[9];
    const float* dzt       = (const float*)d_in[10];
    const float* dzw       = (const float*)d_in[11];
    const float* cost      = (const float*)d_in[12];
    const float* cosu      = (const float*)d_in[13];
    const int*   kbot      = (const int*)d_in[14];
    const float* kappaM    = (const float*)d_in[15];
    const float* mxl       = (const float*)d_in[16];
    const float* forc      = (const float*)d_in[17];
    const float* forc_surf = (const float*)d_in[18];
    const float* tke       = (const float*)d_in[19];
    const float* dtke      = (const float*)d_in[20];

    float* out_tke  = (float*)d_out;
    float* out_dtke = out_tke + (size_t)NX * NY * NZ * 3;
    float* out_corr = out_dtke + (size_t)NX * NY * NZ * 3;

    // (NX/2)*NY pairs, 4 pairs (waves) per block -> 11264 blocks
    tke_fused<<<dim3((NX / 2) * NY / 4), dim3(64, 4), 0, stream>>>(
        tke, dtke, u, v, w, maskU, maskV, maskW,
        kappaM, mxl, forc, forc_surf, kbot,
        dxt, dxu, dyt, dyu, dzt, dzw, cost, cosu,
        out_tke, out_dtke, out_corr);
}

// Round 11
// 130.739 us; speedup vs baseline: 1.0316x; 1.0316x over previous
//
#include <hip/hip_runtime.h>

#define NX 352
#define NY 256
#define NZ 64

__device__ __forceinline__ float rcpf(float x) { return __builtin_amdgcn_rcpf(x); }

__device__ __forceinline__ float limiter(float cr) {
    return fmaxf(0.f, fmaxf(fminf(1.f, 2.f * cr), fminf(2.f, cr)));
}

// superbee flux; cr-switch uses raw vel sign, uCFL uses velfac*vel
__device__ __forceinline__ float sbflux(float vm1, float v0, float vp1, float vp2,
                                        float mm1, float m0, float mp1,
                                        float vel, float velfac, float rinv_dx)
{
    float rjp = (vp2 - vp1) * mp1;
    float rj  = (vp1 - v0) * m0;
    float rjm = (v0 - vm1) * mm1;
    float fv = velfac * vel;
    float uCFL = fabsf(fv * rinv_dx);
    float rden = (fabsf(rj) < 1e-20f) ? 1e-20f : rj;
    float cr = limiter(((vel > 0.f) ? rjm : rjp) * rcpf(rden));
    return fv * (vp1 + v0) * 0.5f - fabsf(fv) * ((1.f - cr) + uCFL * cr) * rj * 0.5f;
}

__global__ __launch_bounds__(256) void
tke_fused(const float* __restrict__ tke, const float* __restrict__ dtke,
          const float* __restrict__ u, const float* __restrict__ v,
          const float* __restrict__ w,
          const float* __restrict__ maskU, const float* __restrict__ maskV,
          const float* __restrict__ maskW,
          const float* __restrict__ kappaM, const float* __restrict__ mxl,
          const float* __restrict__ forc, const float* __restrict__ forc_surf,
          const int* __restrict__ kbot,
          const float* __restrict__ dxt, const float* __restrict__ dxu,
          const float* __restrict__ dyt, const float* __restrict__ dyu,
          const float* __restrict__ dzt, const float* __restrict__ dzw,
          const float* __restrict__ cost, const float* __restrict__ cosu,
          float* __restrict__ out_tke, float* __restrict__ out_dtke,
          float* __restrict__ out_corr)
{
    const int lane = threadIdx.x;                    // k, 0..63
    const int pr   = blockIdx.x * 4 + threadIdx.y;   // pair id over (NX/2, NY)
    const int ip = pr >> 8;                          // NY = 256
    const int j  = pr & 255;
    const int i0 = ip << 1;                          // even; pair (i0, i0+1)
    // i0 even => both columns interior or both exterior
    const bool interior = (i0 >= 2 && i0 < NX - 2 && j >= 2 && j < NY - 2);

    const unsigned SX = (unsigned)NY * NZ;
    const unsigned colA = (unsigned)i0 * NY + j;
    const unsigned colB = colA + NY;
    const unsigned a1 = colA * NZ + lane;
    const unsigned b1 = a1 + SX;
    const unsigned a3 = 3u * a1, b3 = 3u * b1;

    const unsigned ox = interior ? SX : 0u;
    const unsigned oy = interior ? (unsigned)NZ : 0u;
    const int imA = interior ? i0 - 1 : i0;
    const int jm  = interior ? j - 1 : j;

    // ---------- vector column loads ----------
    const float3 tkA = *reinterpret_cast<const float3*>(tke + a3);
    const float3 tkB = *reinterpret_cast<const float3*>(tke + b3);
    const float3 dtA = *reinterpret_cast<const float3*>(dtke + a3);
    const float3 dtB = *reinterpret_cast<const float3*>(dtke + b3);

    // ---------- shared x-plane stencil loads ----------
    const float t_m2 = tke[(a1 - 2u * ox) * 3], t_m1 = tke[(a1 - ox) * 3];
    const float t_p2 = tke[(b1 + ox) * 3],      t_p3 = tke[(b1 + 2u * ox) * 3];
    const float mw_m2 = maskW[a1 - 2u * ox], mw_m1 = maskW[a1 - ox];
    const float mwA = maskW[a1], mwB = maskW[b1];
    const float mw_p2 = maskW[b1 + ox], mw_p3 = maskW[b1 + 2u * ox];

    // ---------- per-column y-plane loads ----------
    const float tA_ym2 = tke[(a1 - 2u * oy) * 3], tA_ym1 = tke[(a1 - oy) * 3];
    const float tA_yp1 = tke[(a1 + oy) * 3],      tA_yp2 = tke[(a1 + 2u * oy) * 3];
    const float tB_ym2 = tke[(b1 - 2u * oy) * 3], tB_ym1 = tke[(b1 - oy) * 3];
    const float tB_yp1 = tke[(b1 + oy) * 3],      tB_yp2 = tke[(b1 + 2u * oy) * 3];
    const float mwA_ym2 = maskW[a1 - 2u * oy], mwA_ym1 = maskW[a1 - oy];
    const float mwA_yp1 = maskW[a1 + oy],      mwA_yp2 = maskW[a1 + 2u * oy];
    const float mwB_ym2 = maskW[b1 - 2u * oy], mwB_ym1 = maskW[b1 - oy];
    const float mwB_yp1 = maskW[b1 + oy],      mwB_yp2 = maskW[b1 + 2u * oy];

    // velocities + face masks
    const float uA0 = u[(a1 - ox) * 3], uA1 = u[a3], uB1 = u[b3];
    const float vA0 = v[(a1 - oy) * 3], vA1 = v[a3];
    const float vB0 = v[(b1 - oy) * 3], vB1 = v[b3];
    const float wA = w[a3], wB = w[b3];
    const float mUA0 = maskU[a1 - ox], mUA1 = maskU[a1], mUB1 = maskU[b1];
    const float mVA0 = maskV[a1 - oy], mVA1 = maskV[a1];
    const float mVB0 = maskV[b1 - oy], mVB1 = maskV[b1];

    // tridiag inputs
    const float kapA = kappaM[a1], kapB = kappaM[b1];
    const float mxA = mxl[a1], mxB = mxl[b1];
    const float foA = forc[a1], foB = forc[b1];
    const int   ksA = kbot[colA] - 1, ksB = kbot[colB] - 1;
    const float fsA = forc_surf[colA], fsB = forc_surf[colB];

    // lane constants
    const float dzwk         = dzw[lane];
    const float inv_dzwk     = rcpf(dzwk);
    const float dzw_last     = 0.5f * dzw[NZ - 1];
    const float inv_dzw_last = rcpf(dzw_last);
    const float inv_dzt_p    = rcpf(dzt[(lane < NZ - 1) ? lane + 1 : NZ - 1]);

    // ---------- tridiag setup + row-normalize (b -> 1) ----------
    bool waterA, waterB;
    float A0, C0, D0, A1c, C1c, D1c;
    {
        float kp = __shfl_down(kapA, 1);
        float delta = (lane < NZ - 1) ? 0.5f * (kapA + kp) * inv_dzt_p : 0.f;
        float dm = __shfl_up(delta, 1); if (lane == 0) dm = 0.f;
        float diss = 0.7f * sqrtf(fmaxf(0.f, tkA.x)) * rcpf(mxA);
        float a, b;
        if (lane == 0)          { a = 0.f; b = 0.f; }
        else if (lane < NZ - 1) { a = -dm * inv_dzwk; b = 1.f + (delta + dm) * inv_dzwk + diss; }
        else                    { a = -dm * inv_dzw_last; b = 1.f + dm * inv_dzw_last + diss; }
        float bE = 1.f + delta * inv_dzwk + diss;
        float c  = (lane < NZ - 1) ? -delta * inv_dzwk : 0.f;
        float d  = tkA.x + foA;
        if (lane == NZ - 1) d += fsA * inv_dzw_last;
        bool land = interior && (ksA >= 0);
        waterA = land && (lane >= ksA);
        bool edge = land && (lane == ksA);
        float A = (waterA && !edge) ? a : 0.f;
        float B = edge ? bE : (waterA ? b : 1.f);
        float C = waterA ? c : 0.f;
        float D = waterA ? d : 0.f;
        float r = rcpf(B);
        A0 = A * r; C0 = C * r; D0 = D * r;
    }
    {
        float kp = __shfl_down(kapB, 1);
        float delta = (lane < NZ - 1) ? 0.5f * (kapB + kp) * inv_dzt_p : 0.f;
        float dm = __shfl_up(delta, 1); if (lane == 0) dm = 0.f;
        float diss = 0.7f * sqrtf(fmaxf(0.f, tkB.x)) * rcpf(mxB);
        float a, b;
        if (lane == 0)          { a = 0.f; b = 0.f; }
        else if (lane < NZ - 1) { a = -dm * inv_dzwk; b = 1.f + (delta + dm) * inv_dzwk + diss; }
        else                    { a = -dm * inv_dzw_last; b = 1.f + dm * inv_dzw_last + diss; }
        float bE = 1.f + delta * inv_dzwk + diss;
        float c  = (lane < NZ - 1) ? -delta * inv_dzwk : 0.f;
        float d  = tkB.x + foB;
        if (lane == NZ - 1) d += fsB * inv_dzw_last;
        bool land = interior && (ksB >= 0);
        waterB = land && (lane >= ksB);
        bool edge = land && (lane == ksB);
        float A = (waterB && !edge) ? a : 0.f;
        float B = edge ? bE : (waterB ? b : 1.f);
        float C = waterB ? c : 0.f;
        float D = waterB ? d : 0.f;
        float r = rcpf(B);
        A1c = A * r; C1c = C * r; D1c = D * r;
    }

    // ---------- normalized PCR, two interleaved chains ----------
    #pragma unroll
    for (int s = 1; s < NZ; s <<= 1) {
        const bool lo = (lane < s);
        const bool hi = (lane + s >= NZ);
        float am0 = __shfl_up(A0, s),  cm0 = __shfl_up(C0, s),  dm0 = __shfl_up(D0, s);
        float am1 = __shfl_up(A1c, s), cm1 = __shfl_up(C1c, s), dm1 = __shfl_up(D1c, s);
        float ap0 = __shfl_down(A0, s),  cp0 = __shfl_down(C0, s),  dp0 = __shfl_down(D0, s);
        float ap1 = __shfl_down(A1c, s), cp1 = __shfl_down(C1c, s), dp1 = __shfl_down(D1c, s);
        if (lo) { am0 = 0.f; cm0 = 0.f; dm0 = 0.f; am1 = 0.f; cm1 = 0.f; dm1 = 0.f; }
        if (hi) { ap0 = 0.f; cp0 = 0.f; dp0 = 0.f; ap1 = 0.f; cp1 = 0.f; dp1 = 0.f; }
        float r0 = rcpf(1.f - A0 * cm0 - C0 * ap0);
        float r1 = rcpf(1.f - A1c * cm1 - C1c * ap1);
        float nA0 = -A0 * am0 * r0,  nC0 = -C0 * cp0 * r0;
        float nD0 = (D0 - A0 * dm0 - C0 * dp0) * r0;
        float nA1 = -A1c * am1 * r1, nC1 = -C1c * cp1 * r1;
        float nD1 = (D1c - A1c * dm1 - C1c * dp1) * r1;
        A0 = nA0; C0 = nC0; D0 = nD0;
        A1c = nA1; C1c = nC1; D1c = nD1;
    }

    float partialA = waterA ? D0 : tkA.y;
    float partialB = waterB ? D1c : tkB.y;
    if (lane == NZ - 1) {
        float corrA = 0.f, corrB = 0.f;
        if (interior && partialA < 0.f) { corrA = -partialA * dzw_last; partialA = 0.f; }
        if (interior && partialB < 0.f) { corrB = -partialB * dzw_last; partialB = 0.f; }
        out_corr[colA] = corrA;
        out_corr[colB] = corrB;
    }

    // ---------- geometry factors ----------
    const float cj = cost[j];
    const float rdx_m = rcpf(cj * dxt[imA]);        // interface i0-1
    const float rdx_0 = rcpf(cj * dxt[i0]);         // interface i0 / col A divisor
    const float rdx_1 = rcpf(cj * dxt[i0 + 1]);     // interface i0+1 / col B divisor
    const float rdy_j  = rcpf(cj * dyt[j]);
    const float rdy_jm = rcpf(cost[jm] * dyt[jm]);
    const float cu_j = cosu[j], cu_jm = cosu[jm];
    const float cud_j  = cu_j * rcpf(dyu[j]);
    const float cud_jm = cu_jm * rcpf(dyu[jm]);
    const float rdxu_m = rcpf(cj * dxu[imA]);
    const float rdxu_0 = rcpf(cj * dxu[i0]);
    const float rdxu_1 = rcpf(cj * dxu[i0 + 1]);

    // ---------- x advection: 3 interface fluxes (middle shared) ----------
    const float mxf_m1 = mwA * mw_m1;   // maskUtr at i0-1
    const float mxf_0  = mwB * mwA;     // maskUtr at i0
    const float mxf_p1 = mw_p2 * mwB;   // maskUtr at i0+1
    float feA0 = sbflux(t_m2, t_m1, tkA.x, tkB.x,
                        mw_m1 * mw_m2, mxf_m1, mxf_0, uA0, 1.f, rdx_m);
    float feI  = sbflux(t_m1, tkA.x, tkB.x, t_p2,
                        mxf_m1, mxf_0, mxf_p1, uA1, 1.f, rdx_0);
    float feB1 = sbflux(tkA.x, tkB.x, t_p2, t_p3,
                        mxf_0, mxf_p1, mw_p3 * mw_p2, uB1, 1.f, rdx_1);

    // ---------- y advection per column ----------
    float fnA0 = sbflux(tA_ym2, tA_ym1, tkA.x, tA_yp1,
                        mwA_ym1 * mwA_ym2, mwA * mwA_ym1, mwA_yp1 * mwA,
                        vA0, cu_jm, rdy_jm);
    float fnA1 = sbflux(tA_ym1, tkA.x, tA_yp1, tA_yp2,
                        mwA * mwA_ym1, mwA_yp1 * mwA, mwA_yp2 * mwA_yp1,
                        vA1, cu_j, rdy_j);
    float fnB0 = sbflux(tB_ym2, tB_ym1, tkB.x, tB_yp1,
                        mwB_ym1 * mwB_ym2, mwB * mwB_ym1, mwB_yp1 * mwB,
                        vB0, cu_jm, rdy_jm);
    float fnB1 = sbflux(tB_ym1, tkB.x, tB_yp1, tB_yp2,
                        mwB * mwB_ym1, mwB_yp1 * mwB, mwB_yp2 * mwB_yp1,
                        vB1, cu_j, rdy_j);

    // ---------- z advection per column (lane-local + shfl) ----------
    float mwA_km1 = __shfl_up(mwA, 1),  mwA_kp1 = __shfl_down(mwA, 1),  mwA_kp2 = __shfl_down(mwA, 2);
    float mwB_km1 = __shfl_up(mwB, 1),  mwB_kp1 = __shfl_down(mwB, 1),  mwB_kp2 = __shfl_down(mwB, 2);
    float tA_km1 = __shfl_up(tkA.x, 1), tA_kp1 = __shfl_down(tkA.x, 1), tA_kp2 = __shfl_down(tkA.x, 2);
    float tB_km1 = __shfl_up(tkB.x, 1), tB_kp1 = __shfl_down(tkB.x, 1), tB_kp2 = __shfl_down(tkB.x, 2);
    float mm1zA = (lane >= 1) ? mwA * mwA_km1 : 0.f;
    float m0zA  = mwA_kp1 * mwA;
    float mp1zA = (lane + 1 < NZ - 1) ? mwA_kp2 * mwA_kp1 : 0.f;
    float mm1zB = (lane >= 1) ? mwB * mwB_km1 : 0.f;
    float m0zB  = mwB_kp1 * mwB;
    float mp1zB = (lane + 1 < NZ - 1) ? mwB_kp2 * mwB_kp1 : 0.f;
    float ftA = sbflux(tA_km1, tkA.x, tA_kp1, tA_kp2, mm1zA, m0zA, mp1zA, wA, 1.f, inv_dzwk);
    float ftB = sbflux(tB_km1, tkB.x, tB_kp1, tB_kp2, mm1zB, m0zB, mp1zB, wB, 1.f, inv_dzwk);
    float ftA_m1 = __shfl_up(ftA, 1);
    float ftB_m1 = __shfl_up(ftB, 1);

    float vertA, vertB;
    if (lane == 0)           { vertA = -ftA * inv_dzwk;            vertB = -ftB * inv_dzwk; }
    else if (lane < NZ - 1)  { vertA = -(ftA - ftA_m1) * inv_dzwk; vertB = -(ftB - ftB_m1) * inv_dzwk; }
    else                     { vertA = ftA_m1 * inv_dzw_last;      vertB = ftB_m1 * inv_dzw_last; }

    float horA = mwA * (-(feI - feA0) * rdx_0 - (fnA1 - fnA0) * rdy_j);
    float horB = mwB * (-(feB1 - feI) * rdx_1 - (fnB1 - fnB0) * rdy_j);

    // ---------- horizontal diffusion: 3 x-face fluxes (middle shared) ----------
    float feDm = 2000.f * (tkA.x - t_m1)  * rdxu_m * mUA0;
    float feD0 = 2000.f * (tkB.x - tkA.x) * rdxu_0 * mUA1;
    float feDp = 2000.f * (t_p2 - tkB.x)  * rdxu_1 * mUB1;
    float fnD1A = 2000.f * (tA_yp1 - tkA.x) * cud_j  * mVA1;
    float fnD0A = 2000.f * (tkA.x - tA_ym1) * cud_jm * mVA0;
    float fnD1B = 2000.f * (tB_yp1 - tkB.x) * cud_j  * mVB1;
    float fnD0B = 2000.f * (tkB.x - tB_ym1) * cud_jm * mVB0;
    float diffA = interior ? mwA * ((feD0 - feDm) * rdx_0 + (fnD1A - fnD0A) * rdy_j) : 0.f;
    float diffB = interior ? mwB * ((feDp - feD0) * rdx_1 + (fnD1B - fnD0B) * rdy_j) : 0.f;

    const float dtkeA = interior ? (horA + vertA) : dtA.x;
    const float dtkeB = interior ? (horB + vertB) : dtB.x;

    // ---------- dense 12B stores ----------
    float3 otA; otA.x = tkA.x; otA.y = partialA + diffA + 1.6f * dtkeA - 0.6f * dtA.z; otA.z = tkA.z;
    float3 otB; otB.x = tkB.x; otB.y = partialB + diffB + 1.6f * dtkeB - 0.6f * dtB.z; otB.z = tkB.z;
    *reinterpret_cast<float3*>(out_tke + a3) = otA;
    *reinterpret_cast<float3*>(out_tke + b3) = otB;
    float3 odA; odA.x = dtkeA; odA.y = dtA.y; odA.z = dtA.z;
    float3 odB; odB.x = dtkeB; odB.y = dtB.y; odB.z = dtB.z;
    *reinterpret_cast<float3*>(out_dtke + a3) = odA;
    *reinterpret_cast<float3*>(out_dtke + b3) = odB;
}

extern "C" void kernel_launch(void* const* d_in, const int* in_sizes, int n_in,
                              void* d_out, int out_size, void* d_ws, size_t ws_size,
                              hipStream_t stream)
{
    const float* u         = (const float*)d_in[0];
    const float* v         = (const float*)d_in[1];
    const float* w         = (const float*)d_in[2];
    const float* maskU     = (const float*)d_in[3];
    const float* maskV     = (const float*)d_in[4];
    const float* maskW     = (const float*)d_in[5];
    const float* dxt       = (const float*)d_in[6];
    const float* dxu       = (const float*)d_in[7];
    const float* dyt       = (const float*)d_in[8];
    const float* dyu       = (const float*)d_in[9];
    const float* dzt       = (const float*)d_in[10];
    const float* dzw       = (const float*)d_in[11];
    const float* cost      = (const float*)d_in[12];
    const float* cosu      = (const float*)d_in[13];
    const int*   kbot      = (const int*)d_in[14];
    const float* kappaM    = (const float*)d_in[15];
    const float* mxl       = (const float*)d_in[16];
    const float* forc      = (const float*)d_in[17];
    const float* forc_surf = (const float*)d_in[18];
    const float* tke       = (const float*)d_in[19];
    const float* dtke      = (const float*)d_in[20];

    float* out_tke  = (float*)d_out;
    float* out_dtke = out_tke + (size_t)NX * NY * NZ * 3;
    float* out_corr = out_dtke + (size_t)NX * NY * NZ * 3;

    // (NX/2) * NY column pairs, 4 pairs per block
    tke_fused<<<dim3((NX / 2) * NY / 4), dim3(64, 4), 0, stream>>>(
        tke, dtke, u, v, w, maskU, maskV, maskW,
        kappaM, mxl, forc, forc_surf, kbot,
        dxt, dxu, dyt, dyu, dzt, dzw, cost, cosu,
        out_tke, out_dtke, out_corr);
}